// Round 9
// baseline (368.317 us; speedup 1.0000x reference)
//
#include <hip/hip_runtime.h>
#include <math.h>

#define N 512
#define BATCH 128
#define EPS 1e-8f
#define TPB 1024         // 16 waves
#define NW 16
#define KP 320           // max kp for direct LDS path (tri fp16 = 105KB)
#define LN2 0.69314718055994530942f
#define SLD 260          // S row stride (floats)

typedef _Float16 f16;
typedef _Float16 f16x8 __attribute__((ext_vector_type(8)));
typedef float f32x4 __attribute__((ext_vector_type(4)));

// packed fp16 triangle: row r starts 16B-aligned, length rup(r+1,8)
__device__ __forceinline__ int lh_base(int r) {
    const int a = r >> 3, b = r & 7;
    return 8 * (a + 1) * (4 * a + b);
}
#define LH_BYTES 104960      // lh_base(320)*2
#define SCR_W 2560           // per-wave: scr32 [16][20] f32 (1280) + Msc [16][40] f16 (1280)
#define ARENA_SZ (LH_BYTES + NW * SCR_W)   // 145920

// global slab per split-block: G fp16 [256][256] | S fp32 [256][SLD]
#define G_BYTES 131072
#define S_BYTES (256 * SLD * 4)
#define SLAB_BYTES (G_BYTES + S_BYTES)

__device__ __forceinline__ float rdl(float v, int l) {
    return __builtin_bit_cast(float,
        __builtin_amdgcn_readlane(__builtin_bit_cast(int, v), l));
}

__device__ __forceinline__ void tri_map(int e, int* r_out, int* c_out) {
    int rr = (int)((sqrtf(8.0f * (float)e + 1.0f) - 1.0f) * 0.5f);
    while ((((rr + 1) * (rr + 2)) >> 1) <= e) ++rr;
    while (((rr * (rr + 1)) >> 1) > e) --rr;
    *r_out = rr;
    *c_out = e - ((rr * (rr + 1)) >> 1);
}

// ---------- L = B^T B + EPS*I : 64x64 register-tiled ----------
__global__ __launch_bounds__(256) void compute_L(const float* __restrict__ B,
                                                 float* __restrict__ L) {
    const int r0 = blockIdx.x * 64, c0 = blockIdx.y * 64;
    const int tx = threadIdx.x & 15, ty = threadIdx.x >> 4;
    __shared__ float Bi[16][64];
    __shared__ float Bj[16][64];
    float acc[4][4] = {};
    for (int k0 = 0; k0 < N; k0 += 16) {
#pragma unroll
        for (int q = 0; q < 4; ++q) {
            const int e = threadIdx.x + q * 256;
            const int kr = e >> 6, cc = e & 63;
            Bi[kr][cc] = B[(k0 + kr) * N + r0 + cc];
            Bj[kr][cc] = B[(k0 + kr) * N + c0 + cc];
        }
        __syncthreads();
#pragma unroll
        for (int kq = 0; kq < 16; ++kq) {
            float a[4], b[4];
#pragma unroll
            for (int q = 0; q < 4; ++q) {
                a[q] = Bi[kq][ty * 4 + q];
                b[q] = Bj[kq][tx * 4 + q];
            }
#pragma unroll
            for (int i = 0; i < 4; ++i)
#pragma unroll
                for (int j = 0; j < 4; ++j) acc[i][j] = fmaf(a[i], b[j], acc[i][j]);
        }
        __syncthreads();
    }
#pragma unroll
    for (int i = 0; i < 4; ++i) {
        const int r = r0 + ty * 4 + i;
        f32x4 v;
#pragma unroll
        for (int j = 0; j < 4; ++j) {
            const int c = c0 + tx * 4 + j;
            v[j] = acc[i][j] + ((r == c) ? EPS : 0.0f);
        }
        *(f32x4*)(&L[r * N + c0 + tx * 4]) = v;
    }
}

// gather one source entry. MODE 0/1: from L via idx (+add1 diag); MODE 2: from S (lower tri)
template <int MODE>
__device__ __forceinline__ float gath(const float* __restrict__ L,
                                      const float* __restrict__ S, const int* idx,
                                      int k, bool add1, int gr, int gc) {
    if constexpr (MODE <= 1) {
        if (gr < k && gc < k) {
            float v = L[idx[gr] * N + idx[gc]];
            if (add1 && gr == gc) v += 1.0f;
            return v;
        }
        return (gr == gc) ? 1.0f : 0.0f;
    } else {
        if (gr < k && gc < k) {
            const int r2 = gr > gc ? gr : gc, c2 = gr > gc ? gc : gr;
            return S[r2 * SLD + c2];
        }
        return (gr == gc) ? 1.0f : 0.0f;
    }
}

// ---------- left-looking PW=16 Cholesky, ONE barrier per panel ----------
// Absolute tile ownership: wave w owns row-tiles {w, w+16} (strictly-below-diag).
// Diag tile computed REDUNDANTLY by all waves (A-frag == B-frag), so the diag
// factor + inverse chain runs per-wave with zero cross-wave deps. Per-wave LDS
// scratch handles all intra-wave fragment transposes (in-order, no barrier).
// Lh diag-row writes and M are benign races (bitwise-identical on all waves).
template <int MODE, int CT>
__device__ float chol_panels(char* arena, f16* __restrict__ G, const float* __restrict__ S,
                             const float* __restrict__ L, const int* idx,
                             int k, int rows, int ncols, bool add1) {
    const int tid = threadIdx.x;
    const int lane = tid & 63, wv = tid >> 6;
    f16* Lh = (f16*)arena;
    float* scr32 = (float*)(arena + LH_BYTES + wv * SCR_W);
    f16* Msc = (f16*)(arena + LH_BYTES + wv * SCR_W + 1280);
    const int frow = lane & 15, koff = (lane >> 4) * 8;
    const int crow = (lane >> 4) * 4, ccol = lane & 15;
    const int r = lane & 15;
    const int ntile = rows >> 4;
    const int npan = ncols >> 4;

    // gathers for panel 0 (prefetched one panel ahead thereafter)
    f32x4 gd = {}, g_[CT];
#pragma unroll
    for (int it = 0; it < CT; ++it) g_[it] = (f32x4){0.f, 0.f, 0.f, 0.f};
#pragma unroll
    for (int q = 0; q < 4; ++q) gd[q] = gath<MODE>(L, S, idx, k, add1, crow + q, ccol);
#pragma unroll
    for (int it = 0; it < CT; ++it) {
        const int ti = wv + NW * it;
        if (ti > 0 && ti < ntile)
#pragma unroll
            for (int q = 0; q < 4; ++q)
                g_[it][q] = gath<MODE>(L, S, idx, k, add1, 16 * ti + crow + q, ccol);
    }

    float lg2 = 0.0f;
    for (int p = 0; p < npan; ++p) {
        const int jb = p << 4;
        const int nkk = (jb + 31) >> 5;
        const int baseB = lh_base(jb + frow) + koff;
        int baseA_[CT];
        bool val_[CT], isg_[CT];
        f32x4 accd = {0.f, 0.f, 0.f, 0.f};
        f32x4 acc_[CT];
#pragma unroll
        for (int it = 0; it < CT; ++it) {
            const int ti = wv + NW * it;
            val_[it] = (ti > p) && (ti < ntile);
            const int r0 = 16 * (val_[it] ? ti : 0);
            isg_[it] = (MODE == 1) && val_[it] && (r0 >= 256);
            baseA_[it] = isg_[it] ? ((r0 - 256 + frow) * 256 + koff)
                                  : (lh_base(r0 + frow) + koff);
            acc_[it] = (f32x4){0.f, 0.f, 0.f, 0.f};
        }

        // ---- (a) kk-chain, strip-mined 4 chunks; +1 redundant diag MFMA per chunk
        for (int cg = 0; cg < nkk; cg += 4) {
            f16x8 Bv[4], Av[4][CT];
#pragma unroll
            for (int u = 0; u < 4; ++u) {
                const int c = cg + u, kk = c << 5;
                const bool ok = (c < nkk) && (kk + koff < jb);
                Bv[u] = ok ? *(const f16x8*)(&Lh[baseB + kk]) : (f16x8){};
#pragma unroll
                for (int it = 0; it < CT; ++it) {
                    f16x8 vv = {};
                    if (ok && val_[it])
                        vv = isg_[it] ? *(const f16x8*)(&G[baseA_[it] + kk])
                                      : *(const f16x8*)(&Lh[baseA_[it] + kk]);
                    Av[u][it] = vv;
                }
            }
#pragma unroll
            for (int u = 0; u < 4; ++u)
                if (cg + u < nkk) {
                    accd = __builtin_amdgcn_mfma_f32_16x16x32_f16(Bv[u], Bv[u], accd, 0, 0, 0);
#pragma unroll
                    for (int it = 0; it < CT; ++it)
                        if (val_[it])
                            acc_[it] = __builtin_amdgcn_mfma_f32_16x16x32_f16(
                                Av[u][it], Bv[u], acc_[it], 0, 0, 0);
                }
        }

        // ---- (b) redundant per-wave: diag S -> scratch -> row regs -> factor+inverse
#pragma unroll
        for (int q = 0; q < 4; ++q) scr32[(crow + q) * 20 + ccol] = gd[q] - accd[q];
        float row[16], w[16];
#pragma unroll
        for (int c = 0; c < 16; ++c) row[c] = scr32[r * 20 + c];
#pragma unroll
        for (int c = 0; c < 16; ++c) w[c] = (c == r) ? 1.0f : 0.0f;
#pragma unroll
        for (int j = 0; j < 16; ++j) {
            const float piv = rdl(row[j], j);
            lg2 += __log2f(piv);
            const float irs = rsqrtf(piv);
            row[j] *= irs;
            w[j] *= irs;
#pragma unroll
            for (int cc = j + 1; cc < 16; ++cc) {
                const float s = rdl(row[j], cc);
                row[cc] = fmaf(-row[j], s, row[cc]);
                w[cc] = fmaf(-s, w[j], w[cc]);
            }
        }
        if (lane < 16) {   // diag factor rows -> Lh (benign race: identical on all waves)
            f16x8 hv0, hv1;
#pragma unroll
            for (int m = 0; m < 8; ++m) {
                hv0[m] = (f16)row[m];
                hv1[m] = (f16)row[8 + m];
            }
            *(f16x8*)(&Lh[lh_base(jb + lane) + jb]) = hv0;
            if (lane >= 8) *(f16x8*)(&Lh[lh_base(jb + lane) + jb + 8]) = hv1;
        }
        if (lane < 32) {   // own-wave M copy (cols 16..31 zero for the K=32 MFMA)
#pragma unroll
            for (int i = 0; i < 16; ++i)
                Msc[i * 40 + lane] = (lane < 16) ? (f16)w[i] : (f16)0.0f;
        }

        // ---- (c) X = S_tile · M^T per owned tile (same-wave scratch transpose)
        const f16x8 bfM = *(const f16x8*)(&Msc[frow * 40 + koff]);
#pragma unroll
        for (int it = 0; it < CT; ++it) {
            if (val_[it]) {
                const int ti = wv + NW * it;
#pragma unroll
                for (int q = 0; q < 4; ++q)
                    scr32[(crow + q) * 20 + ccol] = g_[it][q] - acc_[it][q];
                f16x8 af = {};
                if (koff < 16) {
                    const f32x4 v0 = *(const f32x4*)(&scr32[frow * 20 + koff]);
                    const f32x4 v1 = *(const f32x4*)(&scr32[frow * 20 + koff + 4]);
#pragma unroll
                    for (int m = 0; m < 4; ++m) {
                        af[m] = (f16)v0[m];
                        af[m + 4] = (f16)v1[m];
                    }
                }
                f32x4 xx = {0.f, 0.f, 0.f, 0.f};
                xx = __builtin_amdgcn_mfma_f32_16x16x32_f16(af, bfM, xx, 0, 0, 0);
#pragma unroll
                for (int q = 0; q < 4; ++q) {
                    const int gr = 16 * ti + crow + q;
                    const f16 h = (f16)xx[q];
                    if (MODE == 1 && gr >= 256) G[(gr - 256) * 256 + jb + ccol] = h;
                    else Lh[lh_base(gr) + jb + ccol] = h;
                }
            }
        }

        // ---- prefetch next panel's gathers (fly across the barrier)
        f32x4 ngd = {}, ng_[CT];
#pragma unroll
        for (int it = 0; it < CT; ++it) ng_[it] = (f32x4){0.f, 0.f, 0.f, 0.f};
        if (p + 1 < npan) {
            const int jb2 = jb + 16;
#pragma unroll
            for (int q = 0; q < 4; ++q)
                ngd[q] = gath<MODE>(L, S, idx, k, add1, jb2 + crow + q, jb2 + ccol);
#pragma unroll
            for (int it = 0; it < CT; ++it) {
                const int ti = wv + NW * it;
                if (ti > p + 1 && ti < ntile)
#pragma unroll
                    for (int q = 0; q < 4; ++q)
                        ng_[it][q] = gath<MODE>(L, S, idx, k, add1, 16 * ti + crow + q, jb2 + ccol);
            }
        }
        __syncthreads();   // the ONE barrier: factor cols jb..jb+15 published
        gd = ngd;
#pragma unroll
        for (int it = 0; it < CT; ++it) g_[it] = ng_[it];
    }
    return lg2;
}

// ---------- S = A22 - G·G^T (split path), 16x16 tiles over lower triangle ----------
__device__ void schur_gemm(const f16* __restrict__ G, float* __restrict__ S,
                           const float* __restrict__ L, const int* idx,
                           int k, int k2p, bool add1) {
    const int tid = threadIdx.x;
    const int lane = tid & 63, wv = tid >> 6;
    const int frow = lane & 15, koff = (lane >> 4) * 8;
    const int crow = (lane >> 4) * 4, ccol = lane & 15;
    const int nt2 = k2p >> 4, TT = (nt2 * (nt2 + 1)) >> 1;
    for (int e = wv; e < TT; e += NW) {
        int R, C;
        tri_map(e, &R, &C);
        const int r0 = R << 4, c0 = C << 4;
        f32x4 g;
#pragma unroll
        for (int q = 0; q < 4; ++q) {
            const int gr = 256 + r0 + crow + q, gc = 256 + c0 + ccol;
            float v;
            if (gr < k && gc < k) {
                v = L[idx[gr] * N + idx[gc]];
                if (add1 && gr == gc) v += 1.0f;
            } else v = (gr == gc) ? 1.0f : 0.0f;
            g[q] = v;
        }
        const int ba = (r0 + frow) * 256 + koff, bb = (c0 + frow) * 256 + koff;
        f32x4 acc = {0.f, 0.f, 0.f, 0.f};
        for (int cg = 0; cg < 8; cg += 4) {
            f16x8 A_[4], B_[4];
#pragma unroll
            for (int u = 0; u < 4; ++u) {
                A_[u] = *(const f16x8*)(&G[ba + ((cg + u) << 5)]);
                B_[u] = *(const f16x8*)(&G[bb + ((cg + u) << 5)]);
            }
#pragma unroll
            for (int u = 0; u < 4; ++u)
                acc = __builtin_amdgcn_mfma_f32_16x16x32_f16(A_[u], B_[u], acc, 0, 0, 0);
        }
#pragma unroll
        for (int q = 0; q < 4; ++q)
            S[(r0 + crow + q) * SLD + c0 + ccol] = g[q] - acc[q];
    }
}

// ---------- one block per batch item; block BATCH = logdet(L+I) ----------
__global__ __launch_bounds__(TPB) void chol_all(const int* __restrict__ x,
                                                const float* __restrict__ L,
                                                char* __restrict__ slabs, int nslabs,
                                                float* __restrict__ logs) {
    const int b = blockIdx.x;
    const int tid = threadIdx.x;
    const int lane = tid & 63, wv = tid >> 6;
    __shared__ __align__(16) char arena[ARENA_SZ];
    __shared__ int idx[N];
    __shared__ int wcnt[NW];

    const bool zc = (b == BATCH);
    const bool inx = tid < N;
    const bool act = zc ? inx : (inx && x[(size_t)b * N + tid] != 0);
    const unsigned long long m = __ballot(act);
    if (lane == 0) wcnt[wv] = __popcll(m);
    __syncthreads();
    int off = 0, ktot = 0;
    for (int q = 0; q < NW; ++q) {
        if (q < wv) off += wcnt[q];
        ktot += wcnt[q];
    }
    if (act) idx[off + __popcll(m & ((1ULL << lane) - 1ULL))] = tid;
    __syncthreads();

    const int k = ktot;
    const int kp = (k + 15) & ~15;

    float lg2;
    if (!zc && kp <= KP) {
        lg2 = chol_panels<0, 2>(arena, nullptr, nullptr, L, idx, k, kp, kp, false);
    } else {
        const int si = zc ? 0 : (nslabs > 1 ? 1 + (b % (nslabs - 1)) : 0);
        char* slab = slabs + (size_t)si * SLAB_BYTES;
        f16* G = (f16*)slab;
        float* S = (float*)(slab + G_BYTES);
        const int k2 = k - 256, k2p = kp - 256;
        lg2 = chol_panels<1, 2>(arena, G, nullptr, L, idx, k, kp, 256, zc);
        schur_gemm(G, S, L, idx, k, k2p, zc);
        __syncthreads();
        lg2 += chol_panels<2, 1>(arena, nullptr, S, L, idx, k2, k2p, k2p, false);
    }
    if (tid == 0) logs[b] = lg2 * LN2;
}

__global__ void finalize(const float* __restrict__ logs, float* __restrict__ out) {
    const int i = threadIdx.x;
    out[i] = logs[i] - logs[BATCH];
}

extern "C" void kernel_launch(void* const* d_in, const int* in_sizes, int n_in,
                              void* d_out, int out_size, void* d_ws, size_t ws_size,
                              hipStream_t stream) {
    const int* x = (const int*)d_in[0];
    const float* B = (const float*)d_in[1];
    float* out = (float*)d_out;

    char* ws = (char*)d_ws;
    const size_t L_bytes = (size_t)N * N * 4;  // 1 MB
    float* L = (float*)ws;
    float* logs = (float*)(ws + L_bytes);
    const size_t head = L_bytes + 4096;
    char* slabs = ws + head;
    int nslabs = (ws_size > head) ? (int)((ws_size - head) / SLAB_BYTES) : 1;
    if (nslabs < 1) nslabs = 1;
    if (nslabs > 9) nslabs = 9;

    compute_L<<<dim3(8, 8), 256, 0, stream>>>(B, L);
    chol_all<<<BATCH + 1, TPB, 0, stream>>>(x, L, slabs, nslabs, logs);
    finalize<<<1, BATCH, 0, stream>>>(logs, out);
}

// Round 10
// 174.324 us; speedup vs baseline: 2.1128x; 2.1128x over previous
//
#include <hip/hip_runtime.h>
#include <math.h>

#define N 512
#define BATCH 128
#define EPS 1e-8f
#define TPB 1024         // 16 waves
#define NW 16
#define KP 304           // max kp for direct LDS path
#define LN2 0.69314718055994530942f
#define SPLIT 144        // zcase/overflow split point (multiple of 16)
#define GSTR 152         // G LDS row stride in halves (mult of 8 -> 16B rows)
#define SLD2 372         // S slab row stride (floats)

typedef _Float16 f16;
typedef _Float16 f16x8 __attribute__((ext_vector_type(8)));
typedef float f32x4 __attribute__((ext_vector_type(4)));

// packed fp16 triangle: row r starts 16B-aligned, length rup(r+1,8)
__device__ __forceinline__ int lh_base(int r) {
    const int a = r >> 3, b = r & 7;
    return 8 * (a + 1) * (4 * a + b);
}

// LDS arena layouts (bytes):
// MODE0 (batch):  Lh(304) 0..94848 | P f16 [512][24] @94848 | M @119424 (end 120704)
// MODE1 (stage1): Lh(144) 0..21888 | G f16 [368][GSTR] @22016..133888 |
//                 P @133888 | M @158464 (end 159744)
// MODE2 (stage2): Lh(368) 0..138368 | P @138368 | M @156032 (end 157312)
#define G1_OFF 22016
#define ARENA_SZ 159744
#define SLAB_BYTES (368 * SLD2 * 4)   // S handoff slab (global), 547584

__device__ __forceinline__ float rdl(float v, int l) {
    return __builtin_bit_cast(float,
        __builtin_amdgcn_readlane(__builtin_bit_cast(int, v), l));
}

__device__ __forceinline__ void tri_map(int e, int* r_out, int* c_out) {
    int rr = (int)((sqrtf(8.0f * (float)e + 1.0f) - 1.0f) * 0.5f);
    while ((((rr + 1) * (rr + 2)) >> 1) <= e) ++rr;
    while (((rr * (rr + 1)) >> 1) > e) --rr;
    *r_out = rr;
    *c_out = e - ((rr * (rr + 1)) >> 1);
}

// ---------- L = B^T B + EPS*I : 64x64 register-tiled ----------
__global__ __launch_bounds__(256) void compute_L(const float* __restrict__ B,
                                                 float* __restrict__ L) {
    const int r0 = blockIdx.x * 64, c0 = blockIdx.y * 64;
    const int tx = threadIdx.x & 15, ty = threadIdx.x >> 4;
    __shared__ float Bi[16][64];
    __shared__ float Bj[16][64];
    float acc[4][4] = {};
    for (int k0 = 0; k0 < N; k0 += 16) {
#pragma unroll
        for (int q = 0; q < 4; ++q) {
            const int e = threadIdx.x + q * 256;
            const int kr = e >> 6, cc = e & 63;
            Bi[kr][cc] = B[(k0 + kr) * N + r0 + cc];
            Bj[kr][cc] = B[(k0 + kr) * N + c0 + cc];
        }
        __syncthreads();
#pragma unroll
        for (int kq = 0; kq < 16; ++kq) {
            float a[4], b[4];
#pragma unroll
            for (int q = 0; q < 4; ++q) {
                a[q] = Bi[kq][ty * 4 + q];
                b[q] = Bj[kq][tx * 4 + q];
            }
#pragma unroll
            for (int i = 0; i < 4; ++i)
#pragma unroll
                for (int j = 0; j < 4; ++j) acc[i][j] = fmaf(a[i], b[j], acc[i][j]);
        }
        __syncthreads();
    }
#pragma unroll
    for (int i = 0; i < 4; ++i) {
        const int r = r0 + ty * 4 + i;
        f32x4 v;
#pragma unroll
        for (int j = 0; j < 4; ++j) {
            const int c = c0 + tx * 4 + j;
            v[j] = acc[i][j] + ((r == c) ? EPS : 0.0f);
        }
        *(f32x4*)(&L[r * N + c0 + tx * 4]) = v;
    }
}

// gather one source entry. MODE 0/1: from L via idx (+add1 diag); MODE 2: from S (lower tri)
template <int MODE>
__device__ __forceinline__ float gath(const float* __restrict__ L,
                                      const float* __restrict__ S, const short* idx,
                                      int k, bool add1, int gr, int gc) {
    if constexpr (MODE <= 1) {
        if (gr < k && gc < k) {
            float v = L[(int)idx[gr] * N + (int)idx[gc]];
            if (add1 && gr == gc) v += 1.0f;
            return v;
        }
        return (gr == gc) ? 1.0f : 0.0f;
    } else {
        if (gr < k && gc < k) {
            const int r2 = gr > gc ? gr : gc, c2 = gr > gc ? gc : gr;
            return S[r2 * SLD2 + c2];
        }
        return (gr == gc) ? 1.0f : 0.0f;
    }
}

// ---------- left-looking PW=16 panel Cholesky (R8 skeleton) ----------
// MODE 0: all rows in LDS Lh.  MODE 1: rows >= SPLIT go to LDS G buffer.
// MODE 2: source = S slab (global). Returns sum(log2(pivots)) on wave 0.
template <int MODE, int CT>
__device__ float chol_panels(char* arena, const float* __restrict__ S,
                             const float* __restrict__ L, const short* idx,
                             int k, int rows, int ncols, bool add1) {
    const int tid = threadIdx.x;
    const int lane = tid & 63, wv = tid >> 6;
    constexpr int p_off = (MODE == 0) ? 94848 : (MODE == 1) ? 133888 : 138368;
    constexpr int m_off = (MODE == 0) ? 119424 : (MODE == 1) ? 158464 : 156032;
    f16* Lh = (f16*)arena;
    f16* Gl = (f16*)(arena + G1_OFF);
    f16* P = (f16*)(arena + p_off);       // [rows_rel][24] fp16 staging
    f16* M = (f16*)(arena + m_off);       // [16][40] fp16
    const int frow = lane & 15, koff = (lane >> 4) * 8;
    const int crow = (lane >> 4) * 4, ccol = lane & 15;

    float lg2 = 0.0f;
    const int npan = ncols >> 4;
    for (int p = 0; p < npan; ++p) {
        const int jb = p << 4;
        const int ntile = (rows - jb) >> 4;

        // tile ownership: wave 0 -> diag only; wave w>=1 -> tiles w, w+15, ...
        int r0_[CT], baseA_[CT];
        bool val_[CT], isg_[CT];
#pragma unroll
        for (int it = 0; it < CT; ++it) {
            const int ti = (wv == 0) ? (it == 0 ? 0 : (1 << 20)) : (wv + 15 * it);
            const bool v = ti < ntile;
            const int r0 = jb + ((v ? ti : 0) << 4);
            r0_[it] = r0;
            val_[it] = v;
            const bool gg = (MODE == 1) && v && (r0 >= SPLIT);
            isg_[it] = gg;
            baseA_[it] = gg ? ((r0 - SPLIT + frow) * GSTR + koff)
                            : (lh_base(r0 + frow) + koff);
        }
        const int baseB = lh_base(jb + frow) + koff;

        // scattered gathers (issued early, consumed at P store)
        f32x4 g_[CT];
#pragma unroll
        for (int it = 0; it < CT; ++it)
            if (val_[it]) {
#pragma unroll
                for (int q = 0; q < 4; ++q)
                    g_[it][q] = gath<MODE>(L, S, idx, k, add1, r0_[it] + crow + q, jb + ccol);
            }

        // ---- (a) kk-chain, strip-mined 4 chunks per group
        const int nkk = (jb + 31) >> 5;
        f32x4 acc_[CT];
#pragma unroll
        for (int it = 0; it < CT; ++it) acc_[it] = (f32x4){0.f, 0.f, 0.f, 0.f};

        for (int cg = 0; cg < nkk; cg += 4) {
            f16x8 A_[4][CT], B_[4];
#pragma unroll
            for (int u = 0; u < 4; ++u) {
                const int c = cg + u;
                const int kk = c << 5;
                const bool ok = (c < nkk) && (kk + koff < jb);
                B_[u] = ok ? *(const f16x8*)(&Lh[baseB + kk]) : (f16x8){};
#pragma unroll
                for (int it = 0; it < CT; ++it) {
                    f16x8 vv = {};
                    if (ok && val_[it]) {
                        if (MODE == 1 && isg_[it]) vv = *(const f16x8*)(&Gl[baseA_[it] + kk]);
                        else vv = *(const f16x8*)(&Lh[baseA_[it] + kk]);
                    }
                    A_[u][it] = vv;
                }
            }
#pragma unroll
            for (int u = 0; u < 4; ++u) {
                if (cg + u < nkk) {
#pragma unroll
                    for (int it = 0; it < CT; ++it)
                        if (val_[it])
                            acc_[it] = __builtin_amdgcn_mfma_f32_16x16x32_f16(
                                A_[u][it], B_[u], acc_[it], 0, 0, 0);
                }
            }
        }

        // P store (own rows, fp16) — LDS in-order per wave, same-wave re-read safe
#pragma unroll
        for (int it = 0; it < CT; ++it)
            if (val_[it]) {
                const int lr = r0_[it] - jb;
#pragma unroll
                for (int q = 0; q < 4; ++q)
                    P[(lr + crow + q) * 24 + ccol] = (f16)(g_[it][q] - acc_[it][q]);
            }

        // own (c) A-frags straight from own P rows (fp16, no convert)
        f16x8 afs[CT];
#pragma unroll
        for (int it = 0; it < CT; ++it) {
            f16x8 af = {};
            if (val_[it] && wv != 0 && koff < 16) {
                const int lr = r0_[it] - jb;
                af = *(const f16x8*)(&P[(lr + frow) * 24 + koff]);
            }
            afs[it] = af;
        }

        // ---- (b) wave 0: factor diag via column ops; inverse as by-product
        if (wv == 0) {
            const int r = lane & 15;
            float row[16], w[16];
#pragma unroll
            for (int c = 0; c < 16; ++c) row[c] = (float)P[r * 24 + c];
#pragma unroll
            for (int c = 0; c < 16; ++c) w[c] = (c == r) ? 1.0f : 0.0f;
#pragma unroll
            for (int j = 0; j < 16; ++j) {
                const float piv = rdl(row[j], j);
                lg2 += __log2f(piv);
                const float irs = rsqrtf(piv);
                row[j] *= irs;
                w[j] *= irs;
#pragma unroll
                for (int cc = j + 1; cc < 16; ++cc) {
                    const float s = rdl(row[j], cc);   // L[cc][j], uniform
                    row[cc] = fmaf(-row[j], s, row[cc]);
                    w[cc] = fmaf(-s, w[j], w[cc]);
                }
            }
            if (lane < 16) {
                f16x8 hv0, hv1;
#pragma unroll
                for (int m = 0; m < 8; ++m) {
                    hv0[m] = (f16)row[m];
                    hv1[m] = (f16)row[8 + m];
                }
                *(f16x8*)(&Lh[lh_base(jb + lane) + jb]) = hv0;
                if (lane >= 8) *(f16x8*)(&Lh[lh_base(jb + lane) + jb + 8]) = hv1;
            }
            if (lane < 32) {
#pragma unroll
                for (int i = 0; i < 16; ++i)
                    M[i * 40 + lane] = (lane < 16) ? (f16)w[i] : (f16)0.0f;
            }
        }
        __syncthreads();            // barrier 1: M + diag factor rows visible

        // ---- (c) X = S_tile · M^T : one MFMA per owned tile
        const f16x8 bfM = *(const f16x8*)(&M[frow * 40 + koff]);
#pragma unroll
        for (int it = 0; it < CT; ++it) {
            if (val_[it] && wv != 0) {
                f32x4 xx = {0.f, 0.f, 0.f, 0.f};
                xx = __builtin_amdgcn_mfma_f32_16x16x32_f16(afs[it], bfM, xx, 0, 0, 0);
#pragma unroll
                for (int q = 0; q < 4; ++q) {
                    const int gr = r0_[it] + crow + q;
                    const f16 h = (f16)xx[q];
                    if (MODE == 1 && gr >= SPLIT) Gl[(gr - SPLIT) * GSTR + jb + ccol] = h;
                    else Lh[lh_base(gr) + jb + ccol] = h;
                }
            }
        }
        __syncthreads();            // barrier 2: factor cols jb..jb+15 published
    }
    return lg2;
}

// ---------- S = A22 - G·G^T, G in LDS; S (fp32) streamed to global ----------
__device__ void schur_gemm(char* arena, float* __restrict__ S,
                           const float* __restrict__ L, const short* idx,
                           int k, int k2p, bool add1) {
    const int tid = threadIdx.x;
    const int lane = tid & 63, wv = tid >> 6;
    const f16* Gl = (const f16*)(arena + G1_OFF);
    const int frow = lane & 15, koff = (lane >> 4) * 8;
    const int crow = (lane >> 4) * 4, ccol = lane & 15;
    const int nt2 = k2p >> 4, TT = (nt2 * (nt2 + 1)) >> 1;
    const int nkk = (SPLIT + 31) >> 5;   // 5
    for (int e = wv; e < TT; e += NW) {
        int R, C;
        tri_map(e, &R, &C);
        const int r0 = R << 4, c0 = C << 4;
        f32x4 g;
#pragma unroll
        for (int q = 0; q < 4; ++q) {
            const int gr = SPLIT + r0 + crow + q, gc = SPLIT + c0 + ccol;
            float v;
            if (gr < k && gc < k) {
                v = L[(int)idx[gr] * N + (int)idx[gc]];
                if (add1 && gr == gc) v += 1.0f;
            } else v = (gr == gc) ? 1.0f : 0.0f;
            g[q] = v;
        }
        const int ba = (r0 + frow) * GSTR + koff, bb = (c0 + frow) * GSTR + koff;
        f32x4 acc = {0.f, 0.f, 0.f, 0.f};
        for (int cg = 0; cg < nkk; cg += 4) {
            f16x8 A_[4], B_[4];
#pragma unroll
            for (int u = 0; u < 4; ++u) {
                const int c = cg + u, kk = c << 5;
                const bool ok = (c < nkk) && (kk + koff < SPLIT);
                A_[u] = ok ? *(const f16x8*)(&Gl[ba + kk]) : (f16x8){};
                B_[u] = ok ? *(const f16x8*)(&Gl[bb + kk]) : (f16x8){};
            }
#pragma unroll
            for (int u = 0; u < 4; ++u)
                if (cg + u < nkk)
                    acc = __builtin_amdgcn_mfma_f32_16x16x32_f16(A_[u], B_[u], acc, 0, 0, 0);
        }
#pragma unroll
        for (int q = 0; q < 4; ++q)
            S[(r0 + crow + q) * SLD2 + c0 + ccol] = g[q] - acc[q];
    }
}

// ---------- one block per batch item; block BATCH = logdet(L+I) ----------
__global__ __launch_bounds__(TPB) void chol_all(const int* __restrict__ x,
                                                const float* __restrict__ L,
                                                char* __restrict__ slabs, int nslabs,
                                                float* __restrict__ logs) {
    const int b = blockIdx.x;
    const int tid = threadIdx.x;
    const int lane = tid & 63, wv = tid >> 6;
    __shared__ __align__(16) char arena[ARENA_SZ];
    __shared__ short idx[N];
    __shared__ int wcnt[NW];

    const bool zc = (b == BATCH);
    const bool inx = tid < N;
    const bool act = zc ? inx : (inx && x[(size_t)b * N + tid] != 0);
    const unsigned long long m = __ballot(act);
    if (lane == 0) wcnt[wv] = __popcll(m);
    __syncthreads();
    int off = 0, ktot = 0;
    for (int q = 0; q < NW; ++q) {
        if (q < wv) off += wcnt[q];
        ktot += wcnt[q];
    }
    if (act) idx[off + __popcll(m & ((1ULL << lane) - 1ULL))] = (short)tid;
    __syncthreads();

    const int k = ktot;
    const int kp = (k + 15) & ~15;

    float lg2;
    if (!zc && kp <= KP) {
        lg2 = chol_panels<0, 2>(arena, nullptr, L, idx, k, kp, kp, false);
    } else {
        const int si = zc ? 0 : (nslabs > 1 ? 1 + (b % (nslabs - 1)) : 0);
        float* S = (float*)(slabs + (size_t)si * SLAB_BYTES);
        const int k2 = k - SPLIT, k2p = kp - SPLIT;
        lg2 = chol_panels<1, 3>(arena, nullptr, L, idx, k, kp, SPLIT, zc);
        schur_gemm(arena, S, L, idx, k, k2p, zc);
        __syncthreads();   // all G reads done before stage2 overwrites the arena
        lg2 += chol_panels<2, 2>(arena, S, L, idx, k2, k2p, k2p, false);
    }
    if (tid == 0) logs[b] = lg2 * LN2;
}

__global__ void finalize(const float* __restrict__ logs, float* __restrict__ out) {
    const int i = threadIdx.x;
    out[i] = logs[i] - logs[BATCH];
}

extern "C" void kernel_launch(void* const* d_in, const int* in_sizes, int n_in,
                              void* d_out, int out_size, void* d_ws, size_t ws_size,
                              hipStream_t stream) {
    const int* x = (const int*)d_in[0];
    const float* B = (const float*)d_in[1];
    float* out = (float*)d_out;

    char* ws = (char*)d_ws;
    const size_t L_bytes = (size_t)N * N * 4;  // 1 MB
    float* L = (float*)ws;
    float* logs = (float*)(ws + L_bytes);
    const size_t head = L_bytes + 4096;
    char* slabs = ws + head;
    int nslabs = (ws_size > head) ? (int)((ws_size - head) / SLAB_BYTES) : 1;
    if (nslabs < 1) nslabs = 1;
    if (nslabs > 9) nslabs = 9;

    compute_L<<<dim3(8, 8), 256, 0, stream>>>(B, L);
    chol_all<<<BATCH + 1, TPB, 0, stream>>>(x, L, slabs, nslabs, logs);
    finalize<<<1, BATCH, 0, stream>>>(logs, out);
}